// Round 9
// baseline (370.850 us; speedup 1.0000x reference)
//
#include <hip/hip_runtime.h>
#include <math.h>

#define NN 50000
#define EE 300000
#define NG 8                   // 7 softmax GATs + 1 plain (sin)
#define NTOT (NG * NN)         // 400000 keys
#define NBKT 782               // buckets of 512 (gat,node) keys
#define BCAP 3584              // slots per bucket (mean 3072, sigma~55 -> 9 sigma margin)
#define TILE 1024              // edges per binA block
#define NBLKE ((EE + TILE - 1) / TILE)   // 293

typedef unsigned short u16;
typedef unsigned int u32;
typedef short bf16x8 __attribute__((ext_vector_type(8)));
typedef float f32x16 __attribute__((ext_vector_type(16)));

__device__ __forceinline__ float b2f(u16 u) { return __uint_as_float(((u32)u) << 16); }
__device__ __forceinline__ u16 f2b(float f) {
    u32 x = __float_as_uint(f);
    u32 lsb = (x >> 16) & 1u;
    return (u16)((x + 0x7fffu + lsb) >> 16);
}

// stub symbol kept
__global__ void HeteroGATLayer_14259291423309_kernel() {}

// ---------------- setup: zero gcur + zij constants (1 launch, was 3) ----------------
struct SetupP {
    int* gcur;
    const float* attn[3]; const float* fcW[3]; const float* fcb[3];
    float* consts;
};

__global__ __launch_bounds__(256) void k_setup(SetupP p) {
    const int i = blockIdx.x * 256 + threadIdx.x;
    if (i < NBKT) p.gcur[i] = 0;
    if (blockIdx.x == 3) {
        const int z = threadIdx.x >> 6, lane = threadIdx.x & 63;
        if (z < 3) {
            float a2 = p.attn[z][128 + lane];
            float x = p.fcW[z][lane] * a2;
            float y = p.fcb[z][lane] * a2;
            #pragma unroll
            for (int off = 32; off; off >>= 1) {
                x += __shfl_down(x, off);
                y += __shfl_down(y, off);
            }
            if (lane == 0) {
                const int co[3] = {0, 10, 12};   // g=0 (temporal), g=5 (ttr), g=6 (rut)
                p.consts[co[z]] = x;
                p.consts[co[z] + 1] = y;
            }
        }
    }
}

// ---------------- projections via MFMA + fused attention dots ----------------
struct ProjP {
    const float* feat[3];
    const float* W[8]; const float* b[8];
    u16* wh;                    // Wh arena base
    int ntile[3]; int tiles[3][4];
    int nvec[8];
    const float* avec[8][4];    // attention sub-vector (64 floats)
    float* dvec[8][4];          // destination (el/er + g*NN)
};

__global__ __launch_bounds__(256) void k_proj(ProjP p) {
    __shared__ u16 sA[64 * 64];      // feat tile (persistent)
    __shared__ u16 sW[64 * 64];      // weight tile
    __shared__ u16 sC[64 * 66];      // C tile, padded stride
    const int f = blockIdx.y;
    const int tid = threadIdx.x;
    const int row0 = blockIdx.x * 64;
    const float* feat = p.feat[f];

    #pragma unroll
    for (int q = 0; q < 4; ++q) {
        int idx = q * 256 + tid;
        int r = idx >> 4;
        int c4 = (idx & 15) * 4;
        int gr = row0 + r;
        if (gr >= NN) gr = NN - 1;
        float4 fv = *(const float4*)(feat + (size_t)gr * 64 + c4);
        *(ushort4*)&sA[r * 64 + c4] = make_ushort4(f2b(fv.x), f2b(fv.y), f2b(fv.z), f2b(fv.w));
    }

    const int wv = tid >> 6, lane = tid & 63;
    const int mrow = (wv & 1) * 32, ncol = (wv >> 1) * 32;
    const int half = lane >> 5, l31 = lane & 31;
    const int nt = p.ntile[f];

    for (int ti = 0; ti < nt; ++ti) {
        const int t = p.tiles[f][ti];
        const float* W = p.W[t];
        #pragma unroll
        for (int q = 0; q < 4; ++q) {
            int idx = q * 256 + tid;
            int r = idx >> 4;
            int c4 = (idx & 15) * 4;
            float4 wv4 = *(const float4*)(W + r * 64 + c4);
            *(ushort4*)&sW[r * 64 + c4] = make_ushort4(f2b(wv4.x), f2b(wv4.y), f2b(wv4.z), f2b(wv4.w));
        }
        __syncthreads();    // sA/sW staged; prev iteration's dots (sC reads) done

        f32x16 acc;
        #pragma unroll
        for (int i = 0; i < 16; ++i) acc[i] = 0.0f;
        #pragma unroll
        for (int k0 = 0; k0 < 64; k0 += 16) {
            bf16x8 af = *(const bf16x8*)&sA[(mrow + l31) * 64 + k0 + half * 8];
            bf16x8 bf = *(const bf16x8*)&sW[(ncol + l31) * 64 + k0 + half * 8];
            acc = __builtin_amdgcn_mfma_f32_32x32x16_bf16(af, bf, acc, 0, 0, 0);
        }

        float bb = p.b[t][ncol + l31];
        u16* whp = p.wh + (size_t)t * NN * 64;
        #pragma unroll
        for (int reg = 0; reg < 16; ++reg) {
            int rowD = (reg & 3) + 8 * (reg >> 2) + 4 * half;
            int gr = row0 + mrow + rowD;
            u16 c16 = f2b(acc[reg] + bb);
            if (gr < NN) whp[(size_t)gr * 64 + ncol + l31] = c16;
            sC[(mrow + rowD) * 66 + ncol + l31] = c16;
        }
        __syncthreads();    // sC complete

        // fused attention dots: thread = (row r, vec j); 64 FMA each
        const int r = tid & 63, j = tid >> 6;
        if (j < p.nvec[t]) {
            const float* av = p.avec[t][j];
            float s = 0.f;
            #pragma unroll
            for (int c = 0; c < 64; c += 4) {
                ushort4 cv = *(const ushort4*)&sC[r * 66 + c];
                float4 a4 = *(const float4*)(av + c);
                s += b2f(cv.x) * a4.x + b2f(cv.y) * a4.y + b2f(cv.z) * a4.z + b2f(cv.w) * a4.w;
            }
            int gr = row0 + r;
            if (gr < NN) p.dvec[t][j][gr] = s;
        }
    }
}

// ---------------- binA: LDS-histogram coarse binning (clustered bucket writes) -----------
// payload: {arena byte offset of src Wh row, f32 raw exp score, f32 sc*w, key&511}
struct BinAP {
    const int* src[8]; const int* dst[8]; const float* w[8];
    const float* el[8]; const float* er[8];
    const float* consts;
    int whoff[8];
    int* gcur; int4* bkt;
};

__global__ __launch_bounds__(256) void k_binA(BinAP p) {
    __shared__ int hist[128];
    const int g = blockIdx.y;
    const int b0 = (g * NN) >> 9;          // first bucket this g can touch
    const int tid = threadIdx.x;
    const int e = blockIdx.x * TILE + tid * 4;
    if (tid < 128) hist[tid] = 0;

    const bool hw = p.w[g] != 0;
    float c1 = 0.f, c0 = 0.f;
    if (g < 7 && hw) { c1 = p.consts[2 * g]; c0 = p.consts[2 * g + 1]; }
    const int wo = p.whoff[g];

    // phase 0: load 4 edges (coalesced 16B/lane) + compute payload into regs
    int sr[4], bl[4], low[4];
    float sc[4], pw[4];
    const bool valid = e < EE;             // EE%4==0 -> whole int4 in range
    if (valid) {
        int4 s4 = *(const int4*)(p.src[g] + e);
        int4 d4 = *(const int4*)(p.dst[g] + e);
        float4 w4 = make_float4(0.f, 0.f, 0.f, 0.f);
        if (hw) w4 = *(const float4*)(p.w[g] + e);
        int ss[4] = {s4.x, s4.y, s4.z, s4.w};
        int dd[4] = {d4.x, d4.y, d4.z, d4.w};
        float ww[4] = {w4.x, w4.y, w4.z, w4.w};
        #pragma unroll
        for (int q = 0; q < 4; ++q) {
            int key = g * NN + dd[q];
            bl[q] = (key >> 9) - b0;       // local bucket idx, <= 98
            low[q] = key & 511;
            sr[q] = wo + (ss[q] << 7);     // arena byte offset of Wh row
            float scv = 1.0f, pwv = 0.0f;
            if (g < 7) {
                scv = p.el[g][ss[q]] + p.er[g][dd[q]];
                if (hw) scv += c1 * ww[q] + c0;
                scv = scv > 0.f ? scv : 0.2f * scv;   // leaky_relu(0.2)
                scv = __expf(scv);
                if (hw) pwv = scv * ww[q];
            }
            sc[q] = scv; pw[q] = pwv;
        }
    }
    __syncthreads();                       // hist zero visible
    // phase 1: LDS histogram
    if (valid) {
        #pragma unroll
        for (int q = 0; q < 4; ++q) atomicAdd(&hist[bl[q]], 1);
    }
    __syncthreads();
    // phase 2: one global atomic per (block,bucket); hist becomes write cursor
    if (tid < 128) {
        int c = hist[tid];
        hist[tid] = c ? atomicAdd(&p.gcur[b0 + tid], c) : 0;
    }
    __syncthreads();
    // phase 3: clustered payload write at globally-reserved positions
    if (valid) {
        #pragma unroll
        for (int q = 0; q < 4; ++q) {
            int pos = atomicAdd(&hist[bl[q]], 1);
            int4 v;
            v.x = sr[q];
            v.y = __float_as_int(sc[q]);
            v.z = __float_as_int(pw[q]);
            v.w = low[q];
            p.bkt[(size_t)(b0 + bl[q]) * BCAP + pos] = v;
        }
    }
}

// ---------------- binB: counting sort in LDS + atomic-free segment sums -----------------
// csr slot (coalesced write): {arena_off, f32 raw sc}
// rowdeg4 per key: {(beg<<10)|deg, f32 inv_den, f32 scw*inv, 0}
__global__ __launch_bounds__(512) void k_binB(const int* __restrict__ gcur,
                                              const int4* __restrict__ bkt,
                                              int2* __restrict__ csr,
                                              int4* __restrict__ rowdeg) {
    __shared__ int2 st2[BCAP];       // 28.7 KB sorted {off, sc}
    __shared__ float st3[BCAP];      // 14.3 KB sorted pw
    __shared__ int hist[512];
    __shared__ int scn[512];
    __shared__ int wsum[8];
    const int b = blockIdx.x;
    const int tid = threadIdx.x;
    int count = gcur[b];
    if (count > BCAP) count = BCAP;
    hist[tid] = 0;
    __syncthreads();
    const int4* src = bkt + (size_t)b * BCAP;
    // pass 1: histogram (global read; L2-hot for pass 2)
    for (int i = tid; i < count; i += 512) atomicAdd(&hist[src[i].w], 1);
    __syncthreads();
    // shuffle-based exclusive scan of 512 counts (3 barriers total)
    int h = hist[tid];
    const int lane = tid & 63, wvi = tid >> 6;
    int incl = h;
    #pragma unroll
    for (int off = 1; off < 64; off <<= 1) {
        int t = __shfl_up(incl, off);
        if (lane >= off) incl += t;
    }
    if (lane == 63) wsum[wvi] = incl;
    __syncthreads();
    int wb = 0;
    #pragma unroll
    for (int w = 0; w < 8; ++w)
        if (w < wvi) wb += wsum[w];
    const int excl = wb + incl - h;
    scn[tid] = excl;
    __syncthreads();
    // pass 2: scatter sorted into LDS
    for (int i = tid; i < count; i += 512) {
        int4 v = src[i];
        int pos = atomicAdd(&scn[v.w], 1);
        st2[pos] = make_int2(v.x, v.y);
        st3[pos] = __int_as_float(v.z);
    }
    __syncthreads();
    // per-key serial segment sums (no atomics, ~deg=6 iters)
    float den = 0.f, sw = 0.f;
    for (int j = 0; j < h; ++j) {
        den += __int_as_float(st2[excl + j].y);
        sw += st3[excl + j];
    }
    const int gkey = b * 512 + tid;
    if (gkey < NTOT) {
        float inv = (gkey >= 7 * NN) ? 1.0f : ((h > 0 && den > 0.f) ? 1.0f / den : 0.f);
        u32 beg = (u32)(b * BCAP + excl);
        rowdeg[gkey] = make_int4((int)((beg << 10) | (u32)h),
                                 __float_as_int(inv), __float_as_int(sw * inv), 0);
    }
    // coalesced sorted csr write
    for (int i = tid; i < count; i += 512) csr[(size_t)b * BCAP + i] = st2[i];
}

// ---------------- gather: LDS-broadcast edge walk (no shuffles) --------------------------
struct GathP {
    int gidx[3][3]; int hasfc[3][3];
    const float* fcW[3][3]; const float* fcb[3][3];
};

// overflow path only (deg > 64, essentially never for Poisson(6))
__device__ __forceinline__ void chunk_acc(const char* whA, int dby, int2 v, int len,
                                          float& vs0, float& vs1) {
    int myS = v.x;
    float mySc = __int_as_float(v.y);
    int k = 0;
    for (; k + 4 <= len; k += 4) {
        int s0 = __shfl(myS, k), s1 = __shfl(myS, k + 1);
        int s2 = __shfl(myS, k + 2), s3 = __shfl(myS, k + 3);
        float a0 = __shfl(mySc, k), a1 = __shfl(mySc, k + 1);
        float a2 = __shfl(mySc, k + 2), a3 = __shfl(mySc, k + 3);
        vs0 += a0 * b2f(*(const u16*)(whA + (u32)(s0 + dby)));
        vs1 += a1 * b2f(*(const u16*)(whA + (u32)(s1 + dby)));
        vs0 += a2 * b2f(*(const u16*)(whA + (u32)(s2 + dby)));
        vs1 += a3 * b2f(*(const u16*)(whA + (u32)(s3 + dby)));
    }
    for (; k < len; ++k) {
        int s = __shfl(myS, k);
        float a = __shfl(mySc, k);
        vs0 += a * b2f(*(const u16*)(whA + (u32)(s + dby)));
    }
}

// one 4-wide step of gat t at slot k: uniform LDS reads (broadcast, zero addr VALU)
#define GSTEP4(t, segP)                                                            \
    {                                                                              \
        int2 e0 = segP[k], e1 = segP[k + 1], e2 = segP[k + 2], e3 = segP[k + 3];   \
        const u16* q0 = (const u16*)(whA + (u32)(e0.x + dby));                     \
        const u16* q1 = (const u16*)(whA + (u32)(e1.x + dby));                     \
        const u16* q2 = (const u16*)(whA + (u32)(e2.x + dby));                     \
        const u16* q3 = (const u16*)(whA + (u32)(e3.x + dby));                     \
        float x0 = b2f(*q0), x1 = b2f(*q1), x2 = b2f(*q2), x3 = b2f(*q3);          \
        vs0[t] += __int_as_float(e0.y) * x0;                                       \
        vs1[t] += __int_as_float(e1.y) * x1;                                       \
        vs0[t] += __int_as_float(e2.y) * x2;                                       \
        vs1[t] += __int_as_float(e3.y) * x3;                                       \
    }

__global__ __launch_bounds__(256) void k_gather(GathP p,
        const int4* __restrict__ rowdeg, const int2* __restrict__ csr,
        const char* __restrict__ whA, float* __restrict__ out) {
    __shared__ int2 sSeg[4][3][64];              // 6 KB: wave-private slices
    const int tg = blockIdx.y;
    const int wv = threadIdx.x >> 6, d = threadIdx.x & 63;
    const int i = blockIdx.x * 4 + wv;           // NN = 12500*4 exactly
    const int dby = 2 * d;
    const int ng = (tg == 0) ? 2 : 3;            // task target has only 2 gats

    // wave-uniform descriptors -> SGPRs
    int len[3]; u32 beg[3]; float inv[3], sw[3];
    #pragma unroll
    for (int t = 0; t < 3; ++t) {
        len[t] = 0; beg[t] = 0; inv[t] = 0.f; sw[t] = 0.f;
        if (t < ng) {
            int4 rv = rowdeg[p.gidx[tg][t] * NN + i];
            int rx = __builtin_amdgcn_readfirstlane(rv.x);
            len[t] = rx & 1023;
            beg[t] = ((u32)rx) >> 10;
            inv[t] = __uint_as_float((u32)__builtin_amdgcn_readfirstlane(rv.y));
            sw[t] = __uint_as_float((u32)__builtin_amdgcn_readfirstlane(rv.z));
        }
    }
    // stage first-chunk slots into wave-private LDS (no barrier: wave-synchronous)
    #pragma unroll
    for (int t = 0; t < 3; ++t) {
        int2 v = (d < len[t]) ? csr[beg[t] + d] : make_int2(0, 0);
        sSeg[wv][t][d] = v;
    }
    const int2* sp0 = sSeg[wv][0];
    const int2* sp1 = sSeg[wv][1];
    const int2* sp2 = sSeg[wv][2];

    const int l0 = len[0] < 64 ? len[0] : 64;
    const int l1 = len[1] < 64 ? len[1] : 64;
    const int l2 = len[2] < 64 ? len[2] : 64;
    int kmax = l0 > l1 ? l0 : l1;
    kmax = kmax > l2 ? kmax : l2;

    float vs0[3] = {0.f, 0.f, 0.f}, vs1[3] = {0.f, 0.f, 0.f};
    // fused interleaved walk; per-gat scalar guards; slots >= len hold {0,0}
    // (0.0 * L1-hot row-0 load — free).
    for (int k = 0; k < kmax; k += 4) {
        if (k < l0) GSTEP4(0, sp0)
        if (k < l1) GSTEP4(1, sp1)
        if (k < l2) GSTEP4(2, sp2)
    }
    // overflow chunks (deg > 64): rare serial path via global csr
    #pragma unroll
    for (int t = 0; t < 3; ++t) {
        if (len[t] > 64) {
            for (u32 base = beg[t] + 64; base < beg[t] + (u32)len[t]; base += 64) {
                int len2 = (int)(beg[t] + (u32)len[t] - base);
                if (len2 > 64) len2 = 64;
                int2 v = (d < len2) ? csr[base + d] : make_int2(0, 0);
                chunk_acc(whA, dby, v, len2, vs0[t], vs1[t]);
            }
        }
    }

    float tot = 0.f;
    #pragma unroll
    for (int t = 0; t < 3; ++t) {
        if (len[t] == 0) continue;
        tot += (vs0[t] + vs1[t]) * inv[t];
        if (p.hasfc[tg][t])
            tot += p.fcW[tg][t][d] * sw[t] + p.fcb[tg][t][d];
    }
    out[((size_t)tg * NN + i) * 64 + d] = tot > 0.f ? tot : 0.f;
}

extern "C" void kernel_launch(void* const* d_in, const int* in_sizes, int n_in,
                              void* d_out, int out_size, void* d_ws, size_t ws_size,
                              hipStream_t stream) {
    (void)in_sizes; (void)n_in; (void)out_size; (void)ws_size;
    const float* feats[3] = {(const float*)d_in[0], (const float*)d_in[1], (const float*)d_in[2]};
    const int* srcs[8];
    const int* dsts[8];
    for (int t = 0; t < 8; ++t) {
        srcs[t] = (const int*)d_in[3 + 2 * t];
        dsts[t] = (const int*)d_in[4 + 2 * t];
    }
    const float* ew0 = (const float*)d_in[19];
    const float* ew1 = (const float*)d_in[20];
    const float* ew2 = (const float*)d_in[21];
    const float* Wm[8];
    const float* bm[8];
    for (int t = 0; t < 8; ++t) {
        Wm[t] = (const float*)d_in[22 + 2 * t];
        bm[t] = (const float*)d_in[23 + 2 * t];
    }
    const float* fcW0 = (const float*)d_in[38];
    const float* fcb0 = (const float*)d_in[39];
    const float* fcW1 = (const float*)d_in[40];
    const float* fcb1 = (const float*)d_in[41];
    const float* fcW2 = (const float*)d_in[42];
    const float* fcb2 = (const float*)d_in[43];
    const float* attn_W          = (const float*)d_in[44];
    const float* attn_ttr_W      = (const float*)d_in[45];
    const float* attn_rut_W      = (const float*)d_in[46];
    const float* attn_assigned_W = (const float*)d_in[47];
    const float* attn_com_W      = (const float*)d_in[48];
    const float* attn_tin_W      = (const float*)d_in[49];
    const float* attn_rin_W      = (const float*)d_in[50];

    // ---- workspace (~128 MB): Wh 51.2 | el/er 2.8 | consts | gcur | rowdeg4 6.4 |
    //                           bkt 44.8 | csr 22.4
    u16* Wh = (u16*)d_ws;
    char* b0 = (char*)d_ws + (size_t)8 * NN * 64 * sizeof(u16);
    float* el     = (float*)b0;
    float* er     = el + (size_t)7 * NN;
    float* consts = er + (size_t)7 * NN;
    int* gcur     = (int*)(consts + 16);
    int4* rowdeg4 = (int4*)(((size_t)(gcur + NBKT) + 15) & ~(size_t)15);
    int4* bkt     = rowdeg4 + NTOT;
    int2* csr     = (int2*)(bkt + (size_t)NBKT * BCAP);

    int g_et[8]   = {0, 1, 2, 3, 4, 6, 7, 5};
    int g_sidx[8] = {0, 1, 2, 3, 4, 6, 7, 5};
    const float* g_w[8] = {ew0, 0, 0, 0, 0, ew1, ew2, 0};

    // 1) setup: zero gcur + zij constants (single launch)
    {
        SetupP sp;
        sp.gcur = gcur;
        sp.attn[0] = attn_W;     sp.fcW[0] = fcW0; sp.fcb[0] = fcb0;
        sp.attn[1] = attn_ttr_W; sp.fcW[1] = fcW1; sp.fcb[1] = fcb1;
        sp.attn[2] = attn_rut_W; sp.fcW[2] = fcW2; sp.fcb[2] = fcb2;
        sp.consts = consts;
        k_setup<<<4, 256, 0, stream>>>(sp);
    }

    // 2) projections (MFMA) + fused el/er dots
    {
        ProjP pp;
        pp.feat[0] = feats[0]; pp.feat[1] = feats[1]; pp.feat[2] = feats[2];
        for (int t = 0; t < 8; ++t) { pp.W[t] = Wm[t]; pp.b[t] = bm[t]; }
        pp.wh = Wh;
        pp.ntile[0] = 4; pp.tiles[0][0] = 0; pp.tiles[0][1] = 1; pp.tiles[0][2] = 3; pp.tiles[0][3] = 6;
        pp.ntile[1] = 3; pp.tiles[1][0] = 2; pp.tiles[1][1] = 4; pp.tiles[1][2] = 7; pp.tiles[1][3] = 0;
        pp.ntile[2] = 1; pp.tiles[2][0] = 5; pp.tiles[2][1] = 0; pp.tiles[2][2] = 0; pp.tiles[2][3] = 0;
        for (int t = 0; t < 8; ++t) {
            pp.nvec[t] = 0;
            for (int j = 0; j < 4; ++j) { pp.avec[t][j] = 0; pp.dvec[t][j] = 0; }
        }
        auto setv = [&](int t, int j, const float* a, float* dv) { pp.avec[t][j] = a; pp.dvec[t][j] = dv; };
        // tile -> el/er dot vectors (el[g] from tile sidx[g], er[g] from tile didx[g])
        pp.nvec[0] = 3; setv(0, 0, attn_W, el);           setv(0, 1, attn_W + 64, er);
                        setv(0, 2, attn_rut_W + 64, er + 6 * NN);
        pp.nvec[1] = 1; setv(1, 0, attn_assigned_W, el + 1 * NN);
        pp.nvec[2] = 4; setv(2, 0, attn_com_W, el + 2 * NN); setv(2, 1, attn_assigned_W + 64, er + 1 * NN);
                        setv(2, 2, attn_com_W + 64, er + 2 * NN); setv(2, 3, attn_ttr_W + 64, er + 5 * NN);
        pp.nvec[3] = 1; setv(3, 0, attn_tin_W, el + 3 * NN);
        pp.nvec[4] = 1; setv(4, 0, attn_rin_W, el + 4 * NN);
        pp.nvec[5] = 2; setv(5, 0, attn_tin_W + 64, er + 3 * NN); setv(5, 1, attn_rin_W + 64, er + 4 * NN);
        pp.nvec[6] = 1; setv(6, 0, attn_ttr_W, el + 5 * NN);
        pp.nvec[7] = 1; setv(7, 0, attn_rut_W, el + 6 * NN);
        k_proj<<<dim3(782, 3), 256, 0, stream>>>(pp);
    }

    // 3) bucketed CSR build: binA (clustered writes) -> binB (sort + segment sums)
    {
        BinAP bp;
        for (int g = 0; g < 8; ++g) {
            bp.src[g] = srcs[g_et[g]];
            bp.dst[g] = dsts[g_et[g]];
            bp.w[g] = g_w[g];
            bp.el[g] = (g < 7) ? el + (size_t)g * NN : 0;
            bp.er[g] = (g < 7) ? er + (size_t)g * NN : 0;
            bp.whoff[g] = g_sidx[g] * NN * 128;     // byte offset of gat's Wh tile
        }
        bp.consts = consts;
        bp.gcur = gcur;
        bp.bkt = bkt;
        k_binA<<<dim3(NBLKE, 8), 256, 0, stream>>>(bp);
    }
    k_binB<<<NBKT, 512, 0, stream>>>(gcur, bkt, csr, rowdeg4);

    // 4) gather (single launch, blockIdx.y = target; LDS-broadcast edge walk)
    {
        GathP gp;
        // task: temporal (fc) + rut (fc)  [ng=2, no dummy]
        gp.gidx[0][0] = 0; gp.hasfc[0][0] = 1; gp.fcW[0][0] = fcW0; gp.fcb[0][0] = fcb0;
        gp.gidx[0][1] = 6; gp.hasfc[0][1] = 1; gp.fcW[0][1] = fcW2; gp.fcb[0][1] = fcb2;
        gp.gidx[0][2] = 0; gp.hasfc[0][2] = 0; gp.fcW[0][2] = 0;    gp.fcb[0][2] = 0;
        // worker: assigned + com + ttr (fc)
        gp.gidx[1][0] = 1; gp.hasfc[1][0] = 0; gp.fcW[1][0] = 0;    gp.fcb[1][0] = 0;
        gp.gidx[1][1] = 2; gp.hasfc[1][1] = 0; gp.fcW[1][1] = 0;    gp.fcb[1][1] = 0;
        gp.gidx[1][2] = 5; gp.hasfc[1][2] = 1; gp.fcW[1][2] = fcW1; gp.fcb[1][2] = fcb1;
        // state: tin + win + sin (sin: inv=1 plain sum)
        gp.gidx[2][0] = 3; gp.hasfc[2][0] = 0; gp.fcW[2][0] = 0;    gp.fcb[2][0] = 0;
        gp.gidx[2][1] = 4; gp.hasfc[2][1] = 0; gp.fcW[2][1] = 0;    gp.fcb[2][1] = 0;
        gp.gidx[2][2] = 7; gp.hasfc[2][2] = 0; gp.fcW[2][2] = 0;    gp.fcb[2][2] = 0;
        k_gather<<<dim3(NN / 4, 3), 256, 0, stream>>>(gp, rowdeg4, csr,
                                                      (const char*)Wh, (float*)d_out);
    }
}

// Round 10
// 345.925 us; speedup vs baseline: 1.0721x; 1.0721x over previous
//
#include <hip/hip_runtime.h>
#include <math.h>

#define NN 50000
#define EE 300000
#define NG 8                   // 7 softmax GATs + 1 plain (sin)
#define NTOT (NG * NN)         // 400000 keys
#define NBKT 782               // buckets of 512 (gat,node) keys
#define BCAP 3584              // slots per bucket (mean 3072, sigma~55 -> 9 sigma margin)
#define TILE 1024              // edges per binA block
#define NBLKE ((EE + TILE - 1) / TILE)   // 293

typedef unsigned short u16;
typedef unsigned int u32;
typedef short bf16x8 __attribute__((ext_vector_type(8)));
typedef float f32x16 __attribute__((ext_vector_type(16)));

__device__ __forceinline__ float b2f(u16 u) { return __uint_as_float(((u32)u) << 16); }
__device__ __forceinline__ u16 f2b(float f) {
    u32 x = __float_as_uint(f);
    u32 lsb = (x >> 16) & 1u;
    return (u16)((x + 0x7fffu + lsb) >> 16);
}

// stub symbol kept
__global__ void HeteroGATLayer_14259291423309_kernel() {}

// ---------------- setup: zero gcur + zij constants (1 launch) ----------------
struct SetupP {
    int* gcur;
    const float* attn[3]; const float* fcW[3]; const float* fcb[3];
    float* consts;
};

__global__ __launch_bounds__(256) void k_setup(SetupP p) {
    const int i = blockIdx.x * 256 + threadIdx.x;
    if (i < NBKT) p.gcur[i] = 0;
    if (blockIdx.x == 3) {
        const int z = threadIdx.x >> 6, lane = threadIdx.x & 63;
        if (z < 3) {
            float a2 = p.attn[z][128 + lane];
            float x = p.fcW[z][lane] * a2;
            float y = p.fcb[z][lane] * a2;
            #pragma unroll
            for (int off = 32; off; off >>= 1) {
                x += __shfl_down(x, off);
                y += __shfl_down(y, off);
            }
            if (lane == 0) {
                const int co[3] = {0, 10, 12};   // g=0 (temporal), g=5 (ttr), g=6 (rut)
                p.consts[co[z]] = x;
                p.consts[co[z] + 1] = y;
            }
        }
    }
}

// ---------------- projections via MFMA + fused attention dots ----------------
struct ProjP {
    const float* feat[3];
    const float* W[8]; const float* b[8];
    u16* wh;                    // Wh arena base
    int ntile[3]; int tiles[3][4];
    int nvec[8];
    const float* avec[8][4];    // attention sub-vector (64 floats)
    float* dvec[8][4];          // destination (el/er + g*NN)
};

__global__ __launch_bounds__(256) void k_proj(ProjP p) {
    __shared__ u16 sA[64 * 64];      // feat tile (persistent)
    __shared__ u16 sW[64 * 64];      // weight tile
    __shared__ u16 sC[64 * 66];      // C tile, padded stride
    const int f = blockIdx.y;
    const int tid = threadIdx.x;
    const int row0 = blockIdx.x * 64;
    const float* feat = p.feat[f];

    #pragma unroll
    for (int q = 0; q < 4; ++q) {
        int idx = q * 256 + tid;
        int r = idx >> 4;
        int c4 = (idx & 15) * 4;
        int gr = row0 + r;
        if (gr >= NN) gr = NN - 1;
        float4 fv = *(const float4*)(feat + (size_t)gr * 64 + c4);
        *(ushort4*)&sA[r * 64 + c4] = make_ushort4(f2b(fv.x), f2b(fv.y), f2b(fv.z), f2b(fv.w));
    }

    const int wv = tid >> 6, lane = tid & 63;
    const int mrow = (wv & 1) * 32, ncol = (wv >> 1) * 32;
    const int half = lane >> 5, l31 = lane & 31;
    const int nt = p.ntile[f];

    for (int ti = 0; ti < nt; ++ti) {
        const int t = p.tiles[f][ti];
        const float* W = p.W[t];
        #pragma unroll
        for (int q = 0; q < 4; ++q) {
            int idx = q * 256 + tid;
            int r = idx >> 4;
            int c4 = (idx & 15) * 4;
            float4 wv4 = *(const float4*)(W + r * 64 + c4);
            *(ushort4*)&sW[r * 64 + c4] = make_ushort4(f2b(wv4.x), f2b(wv4.y), f2b(wv4.z), f2b(wv4.w));
        }
        __syncthreads();    // sA/sW staged; prev iteration's dots (sC reads) done

        f32x16 acc;
        #pragma unroll
        for (int i = 0; i < 16; ++i) acc[i] = 0.0f;
        #pragma unroll
        for (int k0 = 0; k0 < 64; k0 += 16) {
            bf16x8 af = *(const bf16x8*)&sA[(mrow + l31) * 64 + k0 + half * 8];
            bf16x8 bf = *(const bf16x8*)&sW[(ncol + l31) * 64 + k0 + half * 8];
            acc = __builtin_amdgcn_mfma_f32_32x32x16_bf16(af, bf, acc, 0, 0, 0);
        }

        float bb = p.b[t][ncol + l31];
        u16* whp = p.wh + (size_t)t * NN * 64;
        #pragma unroll
        for (int reg = 0; reg < 16; ++reg) {
            int rowD = (reg & 3) + 8 * (reg >> 2) + 4 * half;
            int gr = row0 + mrow + rowD;
            u16 c16 = f2b(acc[reg] + bb);
            if (gr < NN) whp[(size_t)gr * 64 + ncol + l31] = c16;
            sC[(mrow + rowD) * 66 + ncol + l31] = c16;
        }
        __syncthreads();    // sC complete

        // fused attention dots: thread = (row r, vec j); 64 FMA each
        const int r = tid & 63, j = tid >> 6;
        if (j < p.nvec[t]) {
            const float* av = p.avec[t][j];
            float s = 0.f;
            #pragma unroll
            for (int c = 0; c < 64; c += 4) {
                ushort4 cv = *(const ushort4*)&sC[r * 66 + c];
                float4 a4 = *(const float4*)(av + c);
                s += b2f(cv.x) * a4.x + b2f(cv.y) * a4.y + b2f(cv.z) * a4.z + b2f(cv.w) * a4.w;
            }
            int gr = row0 + r;
            if (gr < NN) p.dvec[t][j][gr] = s;
        }
    }
}

// ---------------- binA: LDS-histogram coarse binning (clustered bucket writes) -----------
// payload: {arena byte offset of src Wh row, f32 raw exp score, f32 sc*w, key&511}
struct BinAP {
    const int* src[8]; const int* dst[8]; const float* w[8];
    const float* el[8]; const float* er[8];
    const float* consts;
    int whoff[8];
    int* gcur; int4* bkt;
};

__global__ __launch_bounds__(256) void k_binA(BinAP p) {
    __shared__ int hist[128];
    const int g = blockIdx.y;
    const int b0 = (g * NN) >> 9;          // first bucket this g can touch
    const int tid = threadIdx.x;
    const int e = blockIdx.x * TILE + tid * 4;
    if (tid < 128) hist[tid] = 0;

    const bool hw = p.w[g] != 0;
    float c1 = 0.f, c0 = 0.f;
    if (g < 7 && hw) { c1 = p.consts[2 * g]; c0 = p.consts[2 * g + 1]; }
    const int wo = p.whoff[g];

    // phase 0: load 4 edges (coalesced 16B/lane) + compute payload into regs
    int sr[4], bl[4], low[4];
    float sc[4], pw[4];
    const bool valid = e < EE;             // EE%4==0 -> whole int4 in range
    if (valid) {
        int4 s4 = *(const int4*)(p.src[g] + e);
        int4 d4 = *(const int4*)(p.dst[g] + e);
        float4 w4 = make_float4(0.f, 0.f, 0.f, 0.f);
        if (hw) w4 = *(const float4*)(p.w[g] + e);
        int ss[4] = {s4.x, s4.y, s4.z, s4.w};
        int dd[4] = {d4.x, d4.y, d4.z, d4.w};
        float ww[4] = {w4.x, w4.y, w4.z, w4.w};
        #pragma unroll
        for (int q = 0; q < 4; ++q) {
            int key = g * NN + dd[q];
            bl[q] = (key >> 9) - b0;       // local bucket idx, <= 98
            low[q] = key & 511;
            sr[q] = wo + (ss[q] << 7);     // arena byte offset of Wh row
            float scv = 1.0f, pwv = 0.0f;
            if (g < 7) {
                scv = p.el[g][ss[q]] + p.er[g][dd[q]];
                if (hw) scv += c1 * ww[q] + c0;
                scv = scv > 0.f ? scv : 0.2f * scv;   // leaky_relu(0.2)
                scv = __expf(scv);
                if (hw) pwv = scv * ww[q];
            }
            sc[q] = scv; pw[q] = pwv;
        }
    }
    __syncthreads();                       // hist zero visible
    // phase 1: LDS histogram
    if (valid) {
        #pragma unroll
        for (int q = 0; q < 4; ++q) atomicAdd(&hist[bl[q]], 1);
    }
    __syncthreads();
    // phase 2: one global atomic per (block,bucket); hist becomes write cursor
    if (tid < 128) {
        int c = hist[tid];
        hist[tid] = c ? atomicAdd(&p.gcur[b0 + tid], c) : 0;
    }
    __syncthreads();
    // phase 3: clustered payload write at globally-reserved positions
    if (valid) {
        #pragma unroll
        for (int q = 0; q < 4; ++q) {
            int pos = atomicAdd(&hist[bl[q]], 1);
            int4 v;
            v.x = sr[q];
            v.y = __float_as_int(sc[q]);
            v.z = __float_as_int(pw[q]);
            v.w = low[q];
            p.bkt[(size_t)(b0 + bl[q]) * BCAP + pos] = v;
        }
    }
}

// ---------------- binB: counting sort in LDS + atomic-free segment sums -----------------
// csr slot (coalesced write): {arena_off, f32 raw sc}
// rowdeg4 per key: {(beg<<10)|deg, f32 inv_den, f32 scw*inv, 0}
__global__ __launch_bounds__(512) void k_binB(const int* __restrict__ gcur,
                                              const int4* __restrict__ bkt,
                                              int2* __restrict__ csr,
                                              int4* __restrict__ rowdeg) {
    __shared__ int2 st2[BCAP];       // 28.7 KB sorted {off, sc}
    __shared__ float st3[BCAP];      // 14.3 KB sorted pw
    __shared__ int hist[512];
    __shared__ int scn[512];
    __shared__ int wsum[8];
    const int b = blockIdx.x;
    const int tid = threadIdx.x;
    int count = gcur[b];
    if (count > BCAP) count = BCAP;
    hist[tid] = 0;
    __syncthreads();
    const int4* src = bkt + (size_t)b * BCAP;
    // pass 1: histogram (global read; L2-hot for pass 2)
    for (int i = tid; i < count; i += 512) atomicAdd(&hist[src[i].w], 1);
    __syncthreads();
    // shuffle-based exclusive scan of 512 counts (3 barriers total)
    int h = hist[tid];
    const int lane = tid & 63, wvi = tid >> 6;
    int incl = h;
    #pragma unroll
    for (int off = 1; off < 64; off <<= 1) {
        int t = __shfl_up(incl, off);
        if (lane >= off) incl += t;
    }
    if (lane == 63) wsum[wvi] = incl;
    __syncthreads();
    int wb = 0;
    #pragma unroll
    for (int w = 0; w < 8; ++w)
        if (w < wvi) wb += wsum[w];
    const int excl = wb + incl - h;
    scn[tid] = excl;
    __syncthreads();
    // pass 2: scatter sorted into LDS
    for (int i = tid; i < count; i += 512) {
        int4 v = src[i];
        int pos = atomicAdd(&scn[v.w], 1);
        st2[pos] = make_int2(v.x, v.y);
        st3[pos] = __int_as_float(v.z);
    }
    __syncthreads();
    // per-key serial segment sums (no atomics, ~deg=6 iters)
    float den = 0.f, sw = 0.f;
    for (int j = 0; j < h; ++j) {
        den += __int_as_float(st2[excl + j].y);
        sw += st3[excl + j];
    }
    const int gkey = b * 512 + tid;
    if (gkey < NTOT) {
        float inv = (gkey >= 7 * NN) ? 1.0f : ((h > 0 && den > 0.f) ? 1.0f / den : 0.f);
        u32 beg = (u32)(b * BCAP + excl);
        rowdeg[gkey] = make_int4((int)((beg << 10) | (u32)h),
                                 __float_as_int(inv), __float_as_int(sw * inv), 0);
    }
    // coalesced sorted csr write
    for (int i = tid; i < count; i += 512) csr[(size_t)b * BCAP + i] = st2[i];
}

// ---------------- gather: 2 nodes per wave (32 lanes x ushort2 each) ---------------------
// One global-load instruction covers TWO edges (2 rows x 128B); 6 edge chains +
// 12 FMA chains in flight per wave at the same occupancy.
struct GathP {
    int gidx[3][3]; int hasfc[3][3];
    const float* fcW[3][3]; const float* fcb[3][3];
};

// one 4-slot step of gat t: uniform-per-half LDS reads (2-way broadcast, free)
#define GSTEP4(t, sp)                                                              \
    {                                                                              \
        int2 e0 = sp[k], e1 = sp[k + 1], e2 = sp[k + 2], e3 = sp[k + 3];           \
        u32 w0 = *(const u32*)(whA + (u32)(e0.x + dby));                           \
        u32 w1 = *(const u32*)(whA + (u32)(e1.x + dby));                           \
        u32 w2 = *(const u32*)(whA + (u32)(e2.x + dby));                           \
        u32 w3 = *(const u32*)(whA + (u32)(e3.x + dby));                           \
        acc0[t] += __int_as_float(e0.y) * b2f((u16)w0);                            \
        acc1[t] += __int_as_float(e0.y) * b2f((u16)(w0 >> 16));                    \
        acc0[t] += __int_as_float(e1.y) * b2f((u16)w1);                            \
        acc1[t] += __int_as_float(e1.y) * b2f((u16)(w1 >> 16));                    \
        acc0[t] += __int_as_float(e2.y) * b2f((u16)w2);                            \
        acc1[t] += __int_as_float(e2.y) * b2f((u16)(w2 >> 16));                    \
        acc0[t] += __int_as_float(e3.y) * b2f((u16)w3);                            \
        acc1[t] += __int_as_float(e3.y) * b2f((u16)(w3 >> 16));                    \
    }

__global__ __launch_bounds__(256) void k_gather(GathP p,
        const int4* __restrict__ rowdeg, const int2* __restrict__ csr,
        const char* __restrict__ whA, float* __restrict__ out) {
    __shared__ int2 sSeg[4][3][2][64];           // 12 KB: [wave][gat][half][slot]
    const int tg = blockIdx.y;
    const int wv = threadIdx.x >> 6, lane = threadIdx.x & 63;
    const int half = lane >> 5, c = lane & 31;   // this lane: node half, cols 2c,2c+1
    const int i = blockIdx.x * 8 + wv * 2 + half;  // NN = 6250*8 exactly
    const int dby = c * 4;                       // byte offset of ushort2 within row
    const int ng = (tg == 0) ? 2 : 3;            // task target has only 2 gats

    // per-lane (per-half) descriptors; inv/sw stay vector (deg==0 masking per node)
    int lenv[3]; u32 begv[3]; float invv[3], swv[3];
    #pragma unroll
    for (int t = 0; t < 3; ++t) {
        lenv[t] = 0; begv[t] = 0; invv[t] = 0.f; swv[t] = 0.f;
        if (t < ng) {
            int4 rv = rowdeg[p.gidx[tg][t] * NN + i];
            lenv[t] = rv.x & 1023;
            begv[t] = ((u32)rv.x) >> 10;
            invv[t] = __int_as_float(rv.y);
            swv[t] = __int_as_float(rv.z);
        }
    }
    // scalar copies for staging and loop bounds
    int lenA[3], lenB[3], lmax[3]; u32 begA[3], begB[3];
    #pragma unroll
    for (int t = 0; t < 3; ++t) {
        lenA[t] = __builtin_amdgcn_readlane(lenv[t], 0);
        lenB[t] = __builtin_amdgcn_readlane(lenv[t], 32);
        begA[t] = (u32)__builtin_amdgcn_readlane((int)begv[t], 0);
        begB[t] = (u32)__builtin_amdgcn_readlane((int)begv[t], 32);
        lmax[t] = lenA[t] > lenB[t] ? lenA[t] : lenB[t];
    }
    int kall = lmax[0] > lmax[1] ? lmax[0] : lmax[1];
    kall = kall > lmax[2] ? kall : lmax[2];

    float acc0[3] = {0.f, 0.f, 0.f}, acc1[3] = {0.f, 0.f, 0.f};
    for (int cb = 0; cb < kall; cb += 64) {      // single chunk unless deg > 64
        // stage this chunk (both halves; slots >= len hold {0,0})
        #pragma unroll
        for (int t = 0; t < 3; ++t) {
            if (cb < lmax[t]) {
                int2 vA = (lane < lenA[t] - cb) ? csr[begA[t] + cb + lane] : make_int2(0, 0);
                sSeg[wv][t][0][lane] = vA;
                int2 vB = (lane < lenB[t] - cb) ? csr[begB[t] + cb + lane] : make_int2(0, 0);
                sSeg[wv][t][1][lane] = vB;
            }
        }
        // wave-synchronous: no barrier needed for own wave's slice
        const int2* s0 = sSeg[wv][0][half];
        const int2* s1 = sSeg[wv][1][half];
        const int2* s2 = sSeg[wv][2][half];
        int l0 = lmax[0] - cb, l1 = lmax[1] - cb, l2 = lmax[2] - cb;
        if (l0 > 64) l0 = 64;
        if (l1 > 64) l1 = 64;
        if (l2 > 64) l2 = 64;
        int cmax = l0 > l1 ? l0 : l1;
        cmax = cmax > l2 ? cmax : l2;
        for (int k = 0; k < cmax; k += 4) {
            if (k < l0) GSTEP4(0, s0)
            if (k < l1) GSTEP4(1, s1)
            if (k < l2) GSTEP4(2, s2)
        }
    }

    float tot0 = 0.f, tot1 = 0.f;
    #pragma unroll
    for (int t = 0; t < 3; ++t) {
        tot0 += acc0[t] * invv[t];               // invv==0 when deg==0
        tot1 += acc1[t] * invv[t];
        if (p.hasfc[tg][t]) {
            bool he = lenv[t] > 0;               // fc term only when node has edges
            float2 fw = *(const float2*)(p.fcW[tg][t] + 2 * c);
            float2 fb = *(const float2*)(p.fcb[tg][t] + 2 * c);
            tot0 += he ? (fw.x * swv[t] + fb.x) : 0.f;
            tot1 += he ? (fw.y * swv[t] + fb.y) : 0.f;
        }
    }
    float2 o;
    o.x = tot0 > 0.f ? tot0 : 0.f;
    o.y = tot1 > 0.f ? tot1 : 0.f;
    *(float2*)(out + ((size_t)tg * NN + i) * 64 + 2 * c) = o;
}

extern "C" void kernel_launch(void* const* d_in, const int* in_sizes, int n_in,
                              void* d_out, int out_size, void* d_ws, size_t ws_size,
                              hipStream_t stream) {
    (void)in_sizes; (void)n_in; (void)out_size; (void)ws_size;
    const float* feats[3] = {(const float*)d_in[0], (const float*)d_in[1], (const float*)d_in[2]};
    const int* srcs[8];
    const int* dsts[8];
    for (int t = 0; t < 8; ++t) {
        srcs[t] = (const int*)d_in[3 + 2 * t];
        dsts[t] = (const int*)d_in[4 + 2 * t];
    }
    const float* ew0 = (const float*)d_in[19];
    const float* ew1 = (const float*)d_in[20];
    const float* ew2 = (const float*)d_in[21];
    const float* Wm[8];
    const float* bm[8];
    for (int t = 0; t < 8; ++t) {
        Wm[t] = (const float*)d_in[22 + 2 * t];
        bm[t] = (const float*)d_in[23 + 2 * t];
    }
    const float* fcW0 = (const float*)d_in[38];
    const float* fcb0 = (const float*)d_in[39];
    const float* fcW1 = (const float*)d_in[40];
    const float* fcb1 = (const float*)d_in[41];
    const float* fcW2 = (const float*)d_in[42];
    const float* fcb2 = (const float*)d_in[43];
    const float* attn_W          = (const float*)d_in[44];
    const float* attn_ttr_W      = (const float*)d_in[45];
    const float* attn_rut_W      = (const float*)d_in[46];
    const float* attn_assigned_W = (const float*)d_in[47];
    const float* attn_com_W      = (const float*)d_in[48];
    const float* attn_tin_W      = (const float*)d_in[49];
    const float* attn_rin_W      = (const float*)d_in[50];

    // ---- workspace (~128 MB): Wh 51.2 | el/er 2.8 | consts | gcur | rowdeg4 6.4 |
    //                           bkt 44.8 | csr 22.4
    u16* Wh = (u16*)d_ws;
    char* b0 = (char*)d_ws + (size_t)8 * NN * 64 * sizeof(u16);
    float* el     = (float*)b0;
    float* er     = el + (size_t)7 * NN;
    float* consts = er + (size_t)7 * NN;
    int* gcur     = (int*)(consts + 16);
    int4* rowdeg4 = (int4*)(((size_t)(gcur + NBKT) + 15) & ~(size_t)15);
    int4* bkt     = rowdeg4 + NTOT;
    int2* csr     = (int2*)(bkt + (size_t)NBKT * BCAP);

    int g_et[8]   = {0, 1, 2, 3, 4, 6, 7, 5};
    int g_sidx[8] = {0, 1, 2, 3, 4, 6, 7, 5};
    const float* g_w[8] = {ew0, 0, 0, 0, 0, ew1, ew2, 0};

    // 1) setup: zero gcur + zij constants (single launch)
    {
        SetupP sp;
        sp.gcur = gcur;
        sp.attn[0] = attn_W;     sp.fcW[0] = fcW0; sp.fcb[0] = fcb0;
        sp.attn[1] = attn_ttr_W; sp.fcW[1] = fcW1; sp.fcb[1] = fcb1;
        sp.attn[2] = attn_rut_W; sp.fcW[2] = fcW2; sp.fcb[2] = fcb2;
        sp.consts = consts;
        k_setup<<<4, 256, 0, stream>>>(sp);
    }

    // 2) projections (MFMA) + fused el/er dots
    {
        ProjP pp;
        pp.feat[0] = feats[0]; pp.feat[1] = feats[1]; pp.feat[2] = feats[2];
        for (int t = 0; t < 8; ++t) { pp.W[t] = Wm[t]; pp.b[t] = bm[t]; }
        pp.wh = Wh;
        pp.ntile[0] = 4; pp.tiles[0][0] = 0; pp.tiles[0][1] = 1; pp.tiles[0][2] = 3; pp.tiles[0][3] = 6;
        pp.ntile[1] = 3; pp.tiles[1][0] = 2; pp.tiles[1][1] = 4; pp.tiles[1][2] = 7; pp.tiles[1][3] = 0;
        pp.ntile[2] = 1; pp.tiles[2][0] = 5; pp.tiles[2][1] = 0; pp.tiles[2][2] = 0; pp.tiles[2][3] = 0;
        for (int t = 0; t < 8; ++t) {
            pp.nvec[t] = 0;
            for (int j = 0; j < 4; ++j) { pp.avec[t][j] = 0; pp.dvec[t][j] = 0; }
        }
        auto setv = [&](int t, int j, const float* a, float* dv) { pp.avec[t][j] = a; pp.dvec[t][j] = dv; };
        // tile -> el/er dot vectors (el[g] from tile sidx[g], er[g] from tile didx[g])
        pp.nvec[0] = 3; setv(0, 0, attn_W, el);           setv(0, 1, attn_W + 64, er);
                        setv(0, 2, attn_rut_W + 64, er + 6 * NN);
        pp.nvec[1] = 1; setv(1, 0, attn_assigned_W, el + 1 * NN);
        pp.nvec[2] = 4; setv(2, 0, attn_com_W, el + 2 * NN); setv(2, 1, attn_assigned_W + 64, er + 1 * NN);
                        setv(2, 2, attn_com_W + 64, er + 2 * NN); setv(2, 3, attn_ttr_W + 64, er + 5 * NN);
        pp.nvec[3] = 1; setv(3, 0, attn_tin_W, el + 3 * NN);
        pp.nvec[4] = 1; setv(4, 0, attn_rin_W, el + 4 * NN);
        pp.nvec[5] = 2; setv(5, 0, attn_tin_W + 64, er + 3 * NN); setv(5, 1, attn_rin_W + 64, er + 4 * NN);
        pp.nvec[6] = 1; setv(6, 0, attn_ttr_W, el + 5 * NN);
        pp.nvec[7] = 1; setv(7, 0, attn_rut_W, el + 6 * NN);
        k_proj<<<dim3(782, 3), 256, 0, stream>>>(pp);
    }

    // 3) bucketed CSR build: binA (clustered writes) -> binB (sort + segment sums)
    {
        BinAP bp;
        for (int g = 0; g < 8; ++g) {
            bp.src[g] = srcs[g_et[g]];
            bp.dst[g] = dsts[g_et[g]];
            bp.w[g] = g_w[g];
            bp.el[g] = (g < 7) ? el + (size_t)g * NN : 0;
            bp.er[g] = (g < 7) ? er + (size_t)g * NN : 0;
            bp.whoff[g] = g_sidx[g] * NN * 128;     // byte offset of gat's Wh tile
        }
        bp.consts = consts;
        bp.gcur = gcur;
        bp.bkt = bkt;
        k_binA<<<dim3(NBLKE, 8), 256, 0, stream>>>(bp);
    }
    k_binB<<<NBKT, 512, 0, stream>>>(gcur, bkt, csr, rowdeg4);

    // 4) gather (single launch; 2 nodes/wave, 8 nodes/block)
    {
        GathP gp;
        // task: temporal (fc) + rut (fc)  [ng=2]
        gp.gidx[0][0] = 0; gp.hasfc[0][0] = 1; gp.fcW[0][0] = fcW0; gp.fcb[0][0] = fcb0;
        gp.gidx[0][1] = 6; gp.hasfc[0][1] = 1; gp.fcW[0][1] = fcW2; gp.fcb[0][1] = fcb2;
        gp.gidx[0][2] = 0; gp.hasfc[0][2] = 0; gp.fcW[0][2] = fcW0; gp.fcb[0][2] = fcb0;
        // worker: assigned + com + ttr (fc)
        gp.gidx[1][0] = 1; gp.hasfc[1][0] = 0; gp.fcW[1][0] = fcW0; gp.fcb[1][0] = fcb0;
        gp.gidx[1][1] = 2; gp.hasfc[1][1] = 0; gp.fcW[1][1] = fcW0; gp.fcb[1][1] = fcb0;
        gp.gidx[1][2] = 5; gp.hasfc[1][2] = 1; gp.fcW[1][2] = fcW1; gp.fcb[1][2] = fcb1;
        // state: tin + win + sin (sin: inv=1 plain sum)
        gp.gidx[2][0] = 3; gp.hasfc[2][0] = 0; gp.fcW[2][0] = fcW0; gp.fcb[2][0] = fcb0;
        gp.gidx[2][1] = 4; gp.hasfc[2][1] = 0; gp.fcW[2][1] = fcW0; gp.fcb[2][1] = fcb0;
        gp.gidx[2][2] = 7; gp.hasfc[2][2] = 0; gp.fcW[2][2] = fcW0; gp.fcb[2][2] = fcb0;
        k_gather<<<dim3(NN / 8, 3), 256, 0, stream>>>(gp, rowdeg4, csr,
                                                      (const char*)Wh, (float*)d_out);
    }
}